// Round 17
// baseline (606.462 us; speedup 1.0000x reference)
//
#include <hip/hip_runtime.h>
#include <math.h>

#define NN 50000
#define NE 800000
#define NG 1000
#define DN 92
#define DE 41
#define DH 128

typedef float f32x4 __attribute__((ext_vector_type(4)));
typedef short s16x8 __attribute__((ext_vector_type(8)));
typedef __fp16 f16x2 __attribute__((ext_vector_type(2)));
typedef __fp16 f16x8 __attribute__((ext_vector_type(8)));
typedef float f32x4u __attribute__((ext_vector_type(4), aligned(4)));

// ws layout (float units):
//  A      [NN][128] f32         node state
//  Abf    [NN][128] bf16        bf16 mirror of A (gemm input)
//  Pi     [NN][128c][2] f16     dst-side gate proj (f,s interleaved, fp16)
//  Pj     [NN][128c][2] f16     src-side
//  Wcatb  [2][512][128] bf16    node-side gate weights
//  Wte    [2][256][64] f16      edge-side gate weights (frag layout, interleaved n=2c+g)
//  pooled [NG][128] f32
//  cnt/cur[NN] int              sort scratch
//  se4    [NE] uint4            sorted (src, eid, dst, 0) -- single merged stream
//  part/boff [256] int          scan scratch
#define OFF_A     ((size_t)0)
#define OFF_ABF   ((size_t)6400000)
#define OFF_PI    ((size_t)9600000)
#define OFF_PJ    ((size_t)16000000)
#define OFF_WCATB ((size_t)22400000)
#define OFF_WTE   ((size_t)22465536)
#define OFF_POOL  ((size_t)22481920)
#define OFF_CNT   ((size_t)22609920)
#define OFF_CUR   ((size_t)22659920)
#define OFF_SE    ((size_t)22709920)
#define OFF_PART  ((size_t)25909920)
#define OFF_BOFF  ((size_t)25910176)

__device__ __forceinline__ float leaky(float x) { return x > 0.f ? x : 0.01f * x; }
__device__ __forceinline__ ushort f2bf(float x) {
    uint u = __float_as_uint(x);
    return (ushort)((u + 0x7fffu + ((u >> 16) & 1u)) >> 16);
}
__device__ __forceinline__ ushort f2h(float x) {
    union { __fp16 h; ushort u; } c;
    c.h = (__fp16)x;
    return c.u;
}
__device__ __forceinline__ f16x2 u2h(uint u) {
    union { uint u; f16x2 h; } c;
    c.u = u;
    return c.h;
}

// R6-exact gate (full-precision division; rcp — both asm and intrinsic — is the
// confirmed NaN culprit from R7/R8 vs R13 isolation; never reintroduce)
__device__ __forceinline__ float gate(float f, float s) {
    float sg = 1.f / (1.f + __expf(-f));
    float sp = fmaxf(s, 0.f) + __logf(1.f + __expf(-fabsf(s)));
    return sg * sp;
}

// XCD-chunked bijective block swizzle (gridDim must be divisible by 8)
__device__ __forceinline__ int xcd_swz(int bid, int nbid) {
    int cpx = nbid >> 3;
    return (bid & 7) * cpx + (bid >> 3);
}

// pack 8 f32 -> 8 f16 via v_cvt_pkrtz_f16_f32
__device__ __forceinline__ f16x8 pack8h(const float* v) {
    union { f16x2 h[4]; f16x8 s; } r;
#pragma unroll
    for (int p = 0; p < 4; p++)
        r.h[p] = __builtin_amdgcn_cvt_pkrtz(v[2 * p], v[2 * p + 1]);
    return r.s;
}
__device__ __forceinline__ uint pkh1(float a, float b) {
    union { f16x2 h; uint u; } c;
    c.h = __builtin_amdgcn_cvt_pkrtz(a, b);
    return c.u;
}
__device__ __forceinline__ uint cvtpk1(float a, float b) {
    uint r;
    asm("v_cvt_pk_bf16_f32 %0, %1, %2" : "=v"(r) : "v"(a), "v"(b));
    return r;
}

// ---------------- K1: A = leaky_relu(x @ W_node^T + b_node); also Abf ----------------
__global__ __launch_bounds__(128) void k_node_embed(const float* __restrict__ x,
        const float* __restrict__ Wn, const float* __restrict__ bn,
        float* __restrict__ A, ushort* __restrict__ Abf) {
    __shared__ __align__(16) float xs[16 * DN];
    const int n0 = blockIdx.x * 16;
    const int t = threadIdx.x;
    const float4* xg = (const float4*)(x + (size_t)n0 * DN);
    float4* xs4 = (float4*)xs;
    for (int i = t; i < 16 * DN / 4; i += 128) xs4[i] = xg[i];
    __syncthreads();
    const int o = t;
    float acc[16];
#pragma unroll
    for (int n = 0; n < 16; n++) acc[n] = 0.f;
    const float4* Wr = (const float4*)(Wn + (size_t)o * DN);
    for (int kk = 0; kk < DN / 4; kk++) {
        float4 w = Wr[kk];
#pragma unroll
        for (int n = 0; n < 16; n++) {
            float4 a = ((const float4*)(xs + n * DN))[kk];
            acc[n] = fmaf(w.x, a.x, acc[n]);
            acc[n] = fmaf(w.y, a.y, acc[n]);
            acc[n] = fmaf(w.z, a.z, acc[n]);
            acc[n] = fmaf(w.w, a.w, acc[n]);
        }
    }
    float b = bn[o];
#pragma unroll
    for (int n = 0; n < 16; n++) {
        float v = leaky(acc[n] + b);
        A[(size_t)(n0 + n) * DH + o] = v;
        Abf[(size_t)(n0 + n) * DH + o] = f2bf(v);
    }
}

// ------- pack Wcatb[l][cb*128+o][k] = bf16(W{f,s}_l[o][(cb&1)*128 + k]) -------
__global__ __launch_bounds__(128) void k_pack_wcatb(const float* __restrict__ Wf1,
        const float* __restrict__ Ws1, const float* __restrict__ Wf2,
        const float* __restrict__ Ws2, ushort* __restrict__ Wcatb) {
    int b = blockIdx.x;              // 0..1023 = layer*512 + row
    int l = b >> 9, row = b & 511;
    int cb = row >> 7, o = row & 127;
    const float* src;
    if (l == 0) src = (cb < 2) ? Wf1 : Ws1;
    else        src = (cb < 2) ? Wf2 : Ws2;
    int koff = (cb & 1) * 128;
    Wcatb[(size_t)b * 128 + threadIdx.x] = f2bf(src[(size_t)o * 297 + koff + threadIdx.x]);
}

// ------- pack Wte[l][n][k] f16: n = c*2+g (interleaved), k in [0,64) padded from 41 -------
__global__ __launch_bounds__(64) void k_pack_wte(const float* __restrict__ Wf1,
        const float* __restrict__ Ws1, const float* __restrict__ Wf2,
        const float* __restrict__ Ws2, ushort* __restrict__ Wte) {
    int n = blockIdx.x, layer = blockIdx.y, k = threadIdx.x;
    int c = n >> 1, g = n & 1;
    const float* W = layer ? (g ? Ws2 : Wf2) : (g ? Ws1 : Wf1);
    float v = (k < DE) ? W[(size_t)c * 297 + 256 + k] : 0.f;
    Wte[((size_t)(layer * 256 + n)) * 64 + k] = f2h(v);
}

// ---------------- edge sort by dst: histogram / 3-pass scan / scatter ----------------
__global__ __launch_bounds__(256) void k_hist(const int* __restrict__ ei,
        int* __restrict__ cnt) {
    int e = blockIdx.x * 256 + threadIdx.x;
    atomicAdd(&cnt[ei[NE + e]], 1);
}

__global__ __launch_bounds__(256) void k_scan1(const int* __restrict__ cnt,
        int* __restrict__ part) {
    __shared__ int sh[256];
    int i = blockIdx.x * 256 + threadIdx.x;
    sh[threadIdx.x] = (i < NN) ? cnt[i] : 0;
    __syncthreads();
    for (int off = 128; off >= 1; off >>= 1) {
        if (threadIdx.x < off) sh[threadIdx.x] += sh[threadIdx.x + off];
        __syncthreads();
    }
    if (threadIdx.x == 0) part[blockIdx.x] = sh[0];
}

__global__ __launch_bounds__(256) void k_scan2(const int* __restrict__ part,
        int* __restrict__ boff, int nblk) {
    __shared__ int sh[256];
    const int t = threadIdx.x;
    int v = (t < nblk) ? part[t] : 0;
    sh[t] = v;
    __syncthreads();
    for (int off = 1; off < 256; off <<= 1) {
        int u = (t >= off) ? sh[t - off] : 0;
        __syncthreads();
        sh[t] += u;
        __syncthreads();
    }
    if (t < nblk) boff[t] = sh[t] - v;   // exclusive prefix of block sums
}

__global__ __launch_bounds__(256) void k_scan3(const int* __restrict__ cnt,
        const int* __restrict__ boff, int* __restrict__ cur) {
    __shared__ int sh[256];
    const int t = threadIdx.x;
    int i = blockIdx.x * 256 + t;
    int v = (i < NN) ? cnt[i] : 0;
    sh[t] = v;
    __syncthreads();
    for (int off = 1; off < 256; off <<= 1) {
        int u = (t >= off) ? sh[t - off] : 0;
        __syncthreads();
        sh[t] += u;
        __syncthreads();
    }
    if (i < NN) cur[i] = boff[blockIdx.x] + sh[t] - v;
}

// merged single-stream scatter: one 16B write per edge (halves random sectors)
__global__ __launch_bounds__(256) void k_scatter(const int* __restrict__ ei,
        int* __restrict__ cur, uint4* __restrict__ se4) {
    int e = blockIdx.x * 256 + threadIdx.x;
    int src = ei[e], dst = ei[NE + e];
    int pos = atomicAdd(&cur[dst], 1);
    se4[pos] = make_uint4((uint)src, (uint)e, (uint)dst, 0u);
}

// ------- P = Abf @ Wcatb^T via MFMA; block = 32 nodes x N512 (wave w = cb w);
//         epilogue writes f16 (f,s)-interleaved P -------
__global__ __launch_bounds__(256) void k_gemm_P2(const ushort* __restrict__ Abf,
        const ushort* __restrict__ Wcatb, const float* __restrict__ bf,
        const float* __restrict__ bs, ushort* __restrict__ Pi,
        ushort* __restrict__ Pj) {
    __shared__ ushort Alds[32 * 136];
    __shared__ ushort OTi[32 * 264];
    __shared__ ushort OTj[32 * 264];
    const int n0 = blockIdx.x * 32;
    const int t = threadIdx.x;
    const int cb = t >> 6, l = t & 63, m16 = l & 15, g = l >> 4;

    // stage A tile (32 nodes x 128 k, bf16), padded stride 136
    const uint4* Ag = (const uint4*)Abf;
#pragma unroll
    for (int p = 0; p < 2; p++) {
        int row = (t >> 4) + p * 16;
        int node = n0 + row;
        uint4 v = make_uint4(0u, 0u, 0u, 0u);
        if (node < NN) v = Ag[(size_t)node * 16 + (t & 15)];
        *(uint4*)(Alds + row * 136 + (t & 15) * 8) = v;
    }
    __syncthreads();

    const ushort* Bw = Wcatb + (size_t)cb * 128 * 128;
    f32x4 acc[2][8];
#pragma unroll
    for (int mt = 0; mt < 2; mt++)
#pragma unroll
        for (int nt = 0; nt < 8; nt++) acc[mt][nt] = (f32x4){0.f, 0.f, 0.f, 0.f};

    for (int ks = 0; ks < 4; ks++) {
        s16x8 bfr[8];
#pragma unroll
        for (int nt = 0; nt < 8; nt++)
            bfr[nt] = *(const s16x8*)(Bw + ((size_t)(nt * 16 + m16)) * 128 + ks * 32 + g * 8);
        s16x8 afr[2];
#pragma unroll
        for (int mt = 0; mt < 2; mt++)
            afr[mt] = *(const s16x8*)(Alds + (mt * 16 + m16) * 136 + ks * 32 + g * 8);
#pragma unroll
        for (int mt = 0; mt < 2; mt++)
#pragma unroll
            for (int nt = 0; nt < 8; nt++)
                acc[mt][nt] = __builtin_amdgcn_mfma_f32_16x16x32_bf16(
                    afr[mt], bfr[nt], acc[mt][nt], 0, 0, 0);
    }

    // epilogue: bias, f16 convert, interleave into OT, coalesced global write
    float bias[8];
#pragma unroll
    for (int nt = 0; nt < 8; nt++) bias[nt] = 0.f;
    if (cb == 0) {
#pragma unroll
        for (int nt = 0; nt < 8; nt++) bias[nt] = bf[nt * 16 + m16];
    } else if (cb == 2) {
#pragma unroll
        for (int nt = 0; nt < 8; nt++) bias[nt] = bs[nt * 16 + m16];
    }
    ushort* OT = (cb & 1) ? OTj : OTi;
    const int sel = cb >> 1;
#pragma unroll
    for (int mt = 0; mt < 2; mt++)
#pragma unroll
        for (int nt = 0; nt < 8; nt++)
#pragma unroll
            for (int r = 0; r < 4; r++)
                OT[(mt * 16 + g * 4 + r) * 264 + (nt * 16 + m16) * 2 + sel] =
                    f2h(acc[mt][nt][r] + bias[nt]);
    __syncthreads();
#pragma unroll
    for (int p = 0; p < 4; p++) {
        int idx = t + p * 256;
        int row = idx >> 5, col8 = idx & 31;
        int node = n0 + row;
        if (node < NN) {
            *(uint4*)(Pi + (size_t)node * 256 + col8 * 8) = *(const uint4*)(OTi + row * 264 + col8 * 8);
            *(uint4*)(Pj + (size_t)node * 256 + col8 * 8) = *(const uint4*)(OTj + row * 264 + col8 * 8);
        }
    }
}

// ------- edge kernel (R12 best-known + merged se4 stream):
//   prologue: issue se4 window + all Pj gathers + initial Pi row
//   phase1:   E = ea @ Wte via f16 MFMA -> Elds
//   phase2:   consume prefetched registers; Elds reads; gate; run-batched atomics -------
__global__ __launch_bounds__(256) void k_edge(const ushort* __restrict__ Pi,
        const ushort* __restrict__ Pj, const uint4* __restrict__ se4,
        const float* __restrict__ ea, const ushort* __restrict__ Wte,
        float* __restrict__ A) {
    __shared__ ushort Elds[32 * 264];   // [32 edges][256 n + 8 pad] f16
    const int t = threadIdx.x, w = t >> 6, l = t & 63;
    const int bid = xcd_swz(blockIdx.x, gridDim.x);
    const int e0 = bid * 32;
    const int m16 = l & 15, g = l >> 4;

    // ---- prologue: phase-2 gather issue (overlaps phase 1 + barrier) ----
    const uint* PiU = (const uint*)Pi;
    const uint* PjU = (const uint*)Pj;
    const int base = e0 + w * 8;
    uint4 sev = se4[base + (l & 7)];         // one 16B load covers wave's 8 edges
    uint mysrc = sev.x;
    int  mydst = (int)sev.z;
    int dsts[8];
    uint pj0a[8], pj1a[8];
#pragma unroll
    for (int i = 0; i < 8; i++) {
        const int src = __builtin_amdgcn_readlane((int)mysrc, i);
        dsts[i] = __builtin_amdgcn_readlane(mydst, i);
        const uint* pjb = PjU + (size_t)src * 128;   // scalar base -> saddr loads
        pj0a[i] = pjb[l];
        pj1a[i] = pjb[64 + l];
    }
    int dcur = dsts[0];
    const uint* pib0 = PiU + (size_t)dcur * 128;
    uint pi0 = pib0[l], pi1 = pib0[64 + l];

    // ---- phase 1: E = ea_f16 @ Wte (M=32 sorted edges via eid, N=256, K=64) ----
    f16x8 bt[4][2];
#pragma unroll
    for (int nt = 0; nt < 4; nt++)
#pragma unroll
        for (int ks = 0; ks < 2; ks++)
            bt[nt][ks] = *(const f16x8*)(Wte + ((size_t)(w * 64 + nt * 16 + m16)) * 64 + ks * 32 + g * 8);

    f16x8 at[2][2];
#pragma unroll
    for (int mt = 0; mt < 2; mt++) {
        uint4 s2 = se4[e0 + mt * 16 + m16];
        const float* row = ea + (size_t)s2.y * DE;
        f32x4u q0 = *(const f32x4u*)(row + g * 8);
        f32x4u q1 = *(const f32x4u*)(row + g * 8 + 4);
        float v0[8] = {q0.x, q0.y, q0.z, q0.w, q1.x, q1.y, q1.z, q1.w};
        at[mt][0] = pack8h(v0);
        float v1[8] = {0.f, 0.f, 0.f, 0.f, 0.f, 0.f, 0.f, 0.f};
        if (g == 0) {
            f32x4u q2 = *(const f32x4u*)(row + 32);
            f32x4u q3 = *(const f32x4u*)(row + 36);
            v1[0] = q2.x; v1[1] = q2.y; v1[2] = q2.z; v1[3] = q2.w;
            v1[4] = q3.x; v1[5] = q3.y; v1[6] = q3.z; v1[7] = q3.w;
        } else if (g == 1) {
            v1[0] = row[40];
        }
        at[mt][1] = pack8h(v1);
    }

    f32x4 acc[2][4];
#pragma unroll
    for (int mt = 0; mt < 2; mt++)
#pragma unroll
        for (int nt = 0; nt < 4; nt++)
            acc[mt][nt] = (f32x4){0.f, 0.f, 0.f, 0.f};
#pragma unroll
    for (int ks = 0; ks < 2; ks++)
#pragma unroll
        for (int mt = 0; mt < 2; mt++)
#pragma unroll
            for (int nt = 0; nt < 4; nt++)
                acc[mt][nt] = __builtin_amdgcn_mfma_f32_16x16x32_f16(
                    at[mt][ks], bt[nt][ks], acc[mt][nt], 0, 0, 0);

    // write E to LDS: D layout col = lane&15 (n), row = (lane>>4)*4 + reg (m)
#pragma unroll
    for (int mt = 0; mt < 2; mt++)
#pragma unroll
        for (int nt = 0; nt < 4; nt++) {
            uint u01 = pkh1(acc[mt][nt][0], acc[mt][nt][1]);
            uint u23 = pkh1(acc[mt][nt][2], acc[mt][nt][3]);
            const int col = w * 64 + nt * 16 + m16;
            const int r0 = mt * 16 + g * 4;
            Elds[(r0 + 0) * 264 + col] = (ushort)u01;
            Elds[(r0 + 1) * 264 + col] = (ushort)(u01 >> 16);
            Elds[(r0 + 2) * 264 + col] = (ushort)u23;
            Elds[(r0 + 3) * 264 + col] = (ushort)(u23 >> 16);
        }
    __syncthreads();

    // ---- phase 2: consume prefetched data; wave w -> edges w*8..w*8+7 ----
    const uint* ElU = (const uint*)Elds;
    float msg0[8], msg1[8];
#pragma unroll
    for (int i = 0; i < 8; i++) {
        if (dsts[i] != dcur) {                        // wave-uniform scalar branch
            dcur = dsts[i];
            const uint* pb = PiU + (size_t)dcur * 128;
            pi0 = pb[l];
            pi1 = pb[64 + l];
        }
        uint ev0 = ElU[(w * 8 + i) * 132 + l];
        uint ev1 = ElU[(w * 8 + i) * 132 + 64 + l];
        f16x2 t0 = u2h(pi0) + u2h(pj0a[i]) + u2h(ev0);   // v_pk_add_f16
        f16x2 t1 = u2h(pi1) + u2h(pj1a[i]) + u2h(ev1);
        msg0[i] = gate((float)t0.x, (float)t0.y);
        msg1[i] = gate((float)t1.x, (float)t1.y);
    }
    float c0 = msg0[0], c1 = msg1[0];
    int dprev = dsts[0];
#pragma unroll
    for (int i = 1; i < 8; i++) {
        if (dsts[i] == dprev) { c0 += msg0[i]; c1 += msg1[i]; }
        else {
            atomicAdd(A + (size_t)dprev * DH + l, c0);
            atomicAdd(A + (size_t)dprev * DH + 64 + l, c1);
            c0 = msg0[i]; c1 = msg1[i]; dprev = dsts[i];
        }
    }
    atomicAdd(A + (size_t)dprev * DH + l, c0);
    atomicAdd(A + (size_t)dprev * DH + 64 + l, c1);
}

// ---------------- elementwise leaky on A; refresh Abf ----------------
__global__ __launch_bounds__(256) void k_act(float* __restrict__ A,
        ushort* __restrict__ Abf) {
    int i = blockIdx.x * 256 + threadIdx.x;
    float4* A4 = (float4*)A;
    float4 v = A4[i];
    v.x = leaky(v.x); v.y = leaky(v.y); v.z = leaky(v.z); v.w = leaky(v.w);
    A4[i] = v;
    ((uint2*)Abf)[i] = make_uint2(cvtpk1(v.x, v.y), cvtpk1(v.z, v.w));
}

// ------- final activation + embs write + pooling with run-batched atomics -------
__global__ __launch_bounds__(256) void k_finalize(const float* __restrict__ A,
        const int* __restrict__ batch, float* __restrict__ embs,
        float* __restrict__ pooled) {
    const int t = threadIdx.x, w = t >> 6, l = t & 63;
    const int n0 = blockIdx.x * 32 + w * 8;
    int idx = n0 + (l & 7);
    int myb = batch[min(idx, NN - 1)];
    float c0 = 0.f, c1 = 0.f;
    int bprev = __builtin_amdgcn_readlane(myb, 0);
#pragma unroll
    for (int i = 0; i < 8; i++) {
        const int n = n0 + i;
        const int b = __builtin_amdgcn_readlane(myb, i);
        float v0 = 0.f, v1 = 0.f;
        if (n < NN) {
            v0 = leaky(A[(size_t)n * DH + l]);
            v1 = leaky(A[(size_t)n * DH + 64 + l]);
            embs[(size_t)n * DH + l] = v0;
            embs[(size_t)n * DH + 64 + l] = v1;
        }
        if (b != bprev) {
            atomicAdd(pooled + (size_t)bprev * DH + l, c0);
            atomicAdd(pooled + (size_t)bprev * DH + 64 + l, c1);
            c0 = v0; c1 = v1; bprev = b;
        } else {
            c0 += v0; c1 += v1;
        }
    }
    atomicAdd(pooled + (size_t)bprev * DH + l, c0);
    atomicAdd(pooled + (size_t)bprev * DH + 64 + l, c1);
}

// ---------------- head: normalize, W1+leaky, W2 ----------------
__global__ __launch_bounds__(128) void k_head(const float* __restrict__ pooled,
        const float* __restrict__ W1, const float* __restrict__ b1,
        const float* __restrict__ W2, const float* __restrict__ b2,
        float* __restrict__ out) {
    __shared__ __align__(16) float gl[128];
    __shared__ float red[2];
    const int g = blockIdx.x, o = threadIdx.x;
    const int l = o & 63, wid = o >> 6;
    float p = pooled[(size_t)g * DH + o];
    float v = p * p;
#pragma unroll
    for (int off = 32; off >= 1; off >>= 1) v += __shfl_xor(v, off);
    if (l == 0) red[wid] = v;
    __syncthreads();
    float nrm = fmaxf(sqrtf(red[0] + red[1]), 1e-12f);
    float gv = p / nrm;
    gl[o] = gv;
    __syncthreads();
    float gm = b1[o];
    const float4* Wr = (const float4*)(W1 + (size_t)o * DH);
    const float4* gl4 = (const float4*)gl;
    for (int kk = 0; kk < 32; kk++) {
        float4 w = Wr[kk]; float4 a = gl4[kk];
        gm = fmaf(w.x, a.x, gm); gm = fmaf(w.y, a.y, gm);
        gm = fmaf(w.z, a.z, gm); gm = fmaf(w.w, a.w, gm);
    }
    gm = leaky(gm);
    float c = gm * W2[o];
#pragma unroll
    for (int off = 32; off >= 1; off >>= 1) c += __shfl_xor(c, off);
    __syncthreads();
    if (l == 0) red[wid] = c;
    __syncthreads();
    if (o == 0) out[g] = red[0] + red[1] + b2[0];
}

extern "C" void kernel_launch(void* const* d_in, const int* in_sizes, int n_in,
                              void* d_out, int out_size, void* d_ws, size_t ws_size,
                              hipStream_t stream) {
    const float* x    = (const float*)d_in[0];
    const int*   ei   = (const int*)d_in[1];
    const float* ea   = (const float*)d_in[2];
    const int*   batch= (const int*)d_in[3];
    const float* Wn   = (const float*)d_in[4];
    const float* bn   = (const float*)d_in[5];
    const float* Wf1  = (const float*)d_in[6];
    const float* bf1  = (const float*)d_in[7];
    const float* Ws1  = (const float*)d_in[8];
    const float* bs1  = (const float*)d_in[9];
    const float* Wf2  = (const float*)d_in[10];
    const float* bf2  = (const float*)d_in[11];
    const float* Ws2  = (const float*)d_in[12];
    const float* bs2  = (const float*)d_in[13];
    const float* W1   = (const float*)d_in[14];
    const float* b1   = (const float*)d_in[15];
    const float* W2   = (const float*)d_in[16];
    const float* b2   = (const float*)d_in[17];

    float* ws      = (float*)d_ws;
    float*  A      = ws + OFF_A;
    ushort* Abf    = (ushort*)(ws + OFF_ABF);
    ushort* Pi     = (ushort*)(ws + OFF_PI);
    ushort* Pj     = (ushort*)(ws + OFF_PJ);
    ushort* Wcatb  = (ushort*)(ws + OFF_WCATB);
    ushort* Wte    = (ushort*)(ws + OFF_WTE);
    float*  pooled = ws + OFF_POOL;
    int*    cnt    = (int*)(ws + OFF_CNT);
    int*    cur    = (int*)(ws + OFF_CUR);
    uint4*  se4    = (uint4*)(ws + OFF_SE);
    int*    part   = (int*)(ws + OFF_PART);
    int*    boff   = (int*)(ws + OFF_BOFF);
    float* out     = (float*)d_out;
    float* embs    = out + NG;

    const int NBLK = (NN + 255) / 256;   // 196 scan blocks

    hipMemsetAsync(pooled, 0, (size_t)NG * DH * sizeof(float), stream);
    hipMemsetAsync(cnt, 0, (size_t)NN * sizeof(int), stream);
    k_pack_wcatb<<<1024, 128, 0, stream>>>(Wf1, Ws1, Wf2, Ws2, Wcatb);
    k_pack_wte<<<dim3(256, 2), 64, 0, stream>>>(Wf1, Ws1, Wf2, Ws2, Wte);
    k_node_embed<<<NN / 16, 128, 0, stream>>>(x, Wn, bn, A, Abf);

    // sort edges by dst (shared by both layers); 3-pass parallel scan
    k_hist<<<NE / 256, 256, 0, stream>>>(ei, cnt);
    k_scan1<<<NBLK, 256, 0, stream>>>(cnt, part);
    k_scan2<<<1, 256, 0, stream>>>(part, boff, NBLK);
    k_scan3<<<NBLK, 256, 0, stream>>>(cnt, boff, cur);
    k_scatter<<<NE / 256, 256, 0, stream>>>(ei, cur, se4);

    // layer 1
    k_gemm_P2<<<(NN + 31) / 32, 256, 0, stream>>>(Abf, Wcatb, bf1, bs1, Pi, Pj);
    k_edge<<<NE / 32, 256, 0, stream>>>(Pi, Pj, se4, ea, Wte, A);
    k_act<<<(NN * DH / 4) / 256, 256, 0, stream>>>(A, Abf);

    // layer 2
    k_gemm_P2<<<(NN + 31) / 32, 256, 0, stream>>>(Abf, Wcatb + (size_t)512 * 128, bf2, bs2, Pi, Pj);
    k_edge<<<NE / 32, 256, 0, stream>>>(Pi, Pj, se4, ea, Wte + (size_t)256 * 64, A);

    k_finalize<<<(NN + 31) / 32, 256, 0, stream>>>(A, batch, embs, pooled);
    k_head<<<NG, 128, 0, stream>>>(pooled, W1, b1, W2, b2, out);
}

// Round 18
// 590.844 us; speedup vs baseline: 1.0264x; 1.0264x over previous
//
#include <hip/hip_runtime.h>
#include <math.h>

#define NN 50000
#define NE 800000
#define NG 1000
#define DN 92
#define DE 41
#define DH 128

typedef float f32x4 __attribute__((ext_vector_type(4)));
typedef short s16x8 __attribute__((ext_vector_type(8)));
typedef __fp16 f16x2 __attribute__((ext_vector_type(2)));
typedef __fp16 f16x8 __attribute__((ext_vector_type(8)));
typedef float f32x4u __attribute__((ext_vector_type(4), aligned(4)));

// ws layout (float units):
//  A      [NN][128] f32         node state
//  Abf    [NN][128] bf16        bf16 mirror of A (gemm input)
//  Pi     [NN][128c][2] f16     dst-side gate proj (f,s interleaved, fp16)
//  Pj     [NN][128c][2] f16     src-side
//  Wcatb  [2][512][128] bf16    node-side gate weights
//  Wte    [2][256][64] f16      edge-side gate weights (frag layout, interleaved n=2c+g)
//  pooled [NG][128] f32
//  cnt/cur[NN] int              sort scratch
//  se     [NE] uint2            sorted (src, eid)
//  sdst   [NE] int              sorted dst
//  part/boff [256] int          scan scratch
#define OFF_A     ((size_t)0)
#define OFF_ABF   ((size_t)6400000)
#define OFF_PI    ((size_t)9600000)
#define OFF_PJ    ((size_t)16000000)
#define OFF_WCATB ((size_t)22400000)
#define OFF_WTE   ((size_t)22465536)
#define OFF_POOL  ((size_t)22481920)
#define OFF_CNT   ((size_t)22609920)
#define OFF_CUR   ((size_t)22659920)
#define OFF_SE    ((size_t)22709920)
#define OFF_SDST  ((size_t)24309920)
#define OFF_PART  ((size_t)25109920)
#define OFF_BOFF  ((size_t)25110176)

__device__ __forceinline__ float leaky(float x) { return x > 0.f ? x : 0.01f * x; }
__device__ __forceinline__ ushort f2bf(float x) {
    uint u = __float_as_uint(x);
    return (ushort)((u + 0x7fffu + ((u >> 16) & 1u)) >> 16);
}
__device__ __forceinline__ ushort f2h(float x) {
    union { __fp16 h; ushort u; } c;
    c.h = (__fp16)x;
    return c.u;
}
__device__ __forceinline__ f16x2 u2h(uint u) {
    union { uint u; f16x2 h; } c;
    c.u = u;
    return c.h;
}

// R6-exact gate (full-precision division; rcp — both asm and intrinsic — is the
// confirmed NaN culprit from R7/R8 vs R13 isolation; never reintroduce)
__device__ __forceinline__ float gate(float f, float s) {
    float sg = 1.f / (1.f + __expf(-f));
    float sp = fmaxf(s, 0.f) + __logf(1.f + __expf(-fabsf(s)));
    return sg * sp;
}

// XCD-chunked bijective block swizzle (gridDim must be divisible by 8)
__device__ __forceinline__ int xcd_swz(int bid, int nbid) {
    int cpx = nbid >> 3;
    return (bid & 7) * cpx + (bid >> 3);
}

// pack 8 f32 -> 8 f16 via v_cvt_pkrtz_f16_f32
__device__ __forceinline__ f16x8 pack8h(const float* v) {
    union { f16x2 h[4]; f16x8 s; } r;
#pragma unroll
    for (int p = 0; p < 4; p++)
        r.h[p] = __builtin_amdgcn_cvt_pkrtz(v[2 * p], v[2 * p + 1]);
    return r.s;
}
__device__ __forceinline__ uint pkh1(float a, float b) {
    union { f16x2 h; uint u; } c;
    c.h = __builtin_amdgcn_cvt_pkrtz(a, b);
    return c.u;
}
__device__ __forceinline__ uint cvtpk1(float a, float b) {
    uint r;
    asm("v_cvt_pk_bf16_f32 %0, %1, %2" : "=v"(r) : "v"(a), "v"(b));
    return r;
}

// ---------------- K1: A = leaky_relu(x @ W_node^T + b_node); also Abf ----------------
__global__ __launch_bounds__(128) void k_node_embed(const float* __restrict__ x,
        const float* __restrict__ Wn, const float* __restrict__ bn,
        float* __restrict__ A, ushort* __restrict__ Abf) {
    __shared__ __align__(16) float xs[16 * DN];
    const int n0 = blockIdx.x * 16;
    const int t = threadIdx.x;
    const float4* xg = (const float4*)(x + (size_t)n0 * DN);
    float4* xs4 = (float4*)xs;
    for (int i = t; i < 16 * DN / 4; i += 128) xs4[i] = xg[i];
    __syncthreads();
    const int o = t;
    float acc[16];
#pragma unroll
    for (int n = 0; n < 16; n++) acc[n] = 0.f;
    const float4* Wr = (const float4*)(Wn + (size_t)o * DN);
    for (int kk = 0; kk < DN / 4; kk++) {
        float4 w = Wr[kk];
#pragma unroll
        for (int n = 0; n < 16; n++) {
            float4 a = ((const float4*)(xs + n * DN))[kk];
            acc[n] = fmaf(w.x, a.x, acc[n]);
            acc[n] = fmaf(w.y, a.y, acc[n]);
            acc[n] = fmaf(w.z, a.z, acc[n]);
            acc[n] = fmaf(w.w, a.w, acc[n]);
        }
    }
    float b = bn[o];
#pragma unroll
    for (int n = 0; n < 16; n++) {
        float v = leaky(acc[n] + b);
        A[(size_t)(n0 + n) * DH + o] = v;
        Abf[(size_t)(n0 + n) * DH + o] = f2bf(v);
    }
}

// ------- pack Wcatb[l][cb*128+o][k] = bf16(W{f,s}_l[o][(cb&1)*128 + k]) -------
__global__ __launch_bounds__(128) void k_pack_wcatb(const float* __restrict__ Wf1,
        const float* __restrict__ Ws1, const float* __restrict__ Wf2,
        const float* __restrict__ Ws2, ushort* __restrict__ Wcatb) {
    int b = blockIdx.x;              // 0..1023 = layer*512 + row
    int l = b >> 9, row = b & 511;
    int cb = row >> 7, o = row & 127;
    const float* src;
    if (l == 0) src = (cb < 2) ? Wf1 : Ws1;
    else        src = (cb < 2) ? Wf2 : Ws2;
    int koff = (cb & 1) * 128;
    Wcatb[(size_t)b * 128 + threadIdx.x] = f2bf(src[(size_t)o * 297 + koff + threadIdx.x]);
}

// ------- pack Wte[l][n][k] f16: n = c*2+g (interleaved), k in [0,64) padded from 41 -------
__global__ __launch_bounds__(64) void k_pack_wte(const float* __restrict__ Wf1,
        const float* __restrict__ Ws1, const float* __restrict__ Wf2,
        const float* __restrict__ Ws2, ushort* __restrict__ Wte) {
    int n = blockIdx.x, layer = blockIdx.y, k = threadIdx.x;
    int c = n >> 1, g = n & 1;
    const float* W = layer ? (g ? Ws2 : Wf2) : (g ? Ws1 : Wf1);
    float v = (k < DE) ? W[(size_t)c * 297 + 256 + k] : 0.f;
    Wte[((size_t)(layer * 256 + n)) * 64 + k] = f2h(v);
}

// ---------------- edge sort by dst: histogram / 3-pass scan / scatter ----------------
__global__ __launch_bounds__(256) void k_hist(const int* __restrict__ ei,
        int* __restrict__ cnt) {
    int e = blockIdx.x * 256 + threadIdx.x;
    atomicAdd(&cnt[ei[NE + e]], 1);
}

__global__ __launch_bounds__(256) void k_scan1(const int* __restrict__ cnt,
        int* __restrict__ part) {
    __shared__ int sh[256];
    int i = blockIdx.x * 256 + threadIdx.x;
    sh[threadIdx.x] = (i < NN) ? cnt[i] : 0;
    __syncthreads();
    for (int off = 128; off >= 1; off >>= 1) {
        if (threadIdx.x < off) sh[threadIdx.x] += sh[threadIdx.x + off];
        __syncthreads();
    }
    if (threadIdx.x == 0) part[blockIdx.x] = sh[0];
}

__global__ __launch_bounds__(256) void k_scan2(const int* __restrict__ part,
        int* __restrict__ boff, int nblk) {
    __shared__ int sh[256];
    const int t = threadIdx.x;
    int v = (t < nblk) ? part[t] : 0;
    sh[t] = v;
    __syncthreads();
    for (int off = 1; off < 256; off <<= 1) {
        int u = (t >= off) ? sh[t - off] : 0;
        __syncthreads();
        sh[t] += u;
        __syncthreads();
    }
    if (t < nblk) boff[t] = sh[t] - v;   // exclusive prefix of block sums
}

__global__ __launch_bounds__(256) void k_scan3(const int* __restrict__ cnt,
        const int* __restrict__ boff, int* __restrict__ cur) {
    __shared__ int sh[256];
    const int t = threadIdx.x;
    int i = blockIdx.x * 256 + t;
    int v = (i < NN) ? cnt[i] : 0;
    sh[t] = v;
    __syncthreads();
    for (int off = 1; off < 256; off <<= 1) {
        int u = (t >= off) ? sh[t - off] : 0;
        __syncthreads();
        sh[t] += u;
        __syncthreads();
    }
    if (i < NN) cur[i] = boff[blockIdx.x] + sh[t] - v;
}

__global__ __launch_bounds__(256) void k_scatter(const int* __restrict__ ei,
        int* __restrict__ cur, uint2* __restrict__ se, int* __restrict__ sdst) {
    int e = blockIdx.x * 256 + threadIdx.x;
    int src = ei[e], dst = ei[NE + e];
    int pos = atomicAdd(&cur[dst], 1);
    se[pos] = make_uint2((uint)src, (uint)e);
    sdst[pos] = dst;
}

// ------- P = Abf @ Wcatb^T via MFMA; block = 32 nodes x N512 (wave w = cb w);
//         epilogue writes f16 (f,s)-interleaved P -------
__global__ __launch_bounds__(256) void k_gemm_P2(const ushort* __restrict__ Abf,
        const ushort* __restrict__ Wcatb, const float* __restrict__ bf,
        const float* __restrict__ bs, ushort* __restrict__ Pi,
        ushort* __restrict__ Pj) {
    __shared__ ushort Alds[32 * 136];
    __shared__ ushort OTi[32 * 264];
    __shared__ ushort OTj[32 * 264];
    const int n0 = blockIdx.x * 32;
    const int t = threadIdx.x;
    const int cb = t >> 6, l = t & 63, m16 = l & 15, g = l >> 4;

    // stage A tile (32 nodes x 128 k, bf16), padded stride 136
    const uint4* Ag = (const uint4*)Abf;
#pragma unroll
    for (int p = 0; p < 2; p++) {
        int row = (t >> 4) + p * 16;
        int node = n0 + row;
        uint4 v = make_uint4(0u, 0u, 0u, 0u);
        if (node < NN) v = Ag[(size_t)node * 16 + (t & 15)];
        *(uint4*)(Alds + row * 136 + (t & 15) * 8) = v;
    }
    __syncthreads();

    const ushort* Bw = Wcatb + (size_t)cb * 128 * 128;
    f32x4 acc[2][8];
#pragma unroll
    for (int mt = 0; mt < 2; mt++)
#pragma unroll
        for (int nt = 0; nt < 8; nt++) acc[mt][nt] = (f32x4){0.f, 0.f, 0.f, 0.f};

    for (int ks = 0; ks < 4; ks++) {
        s16x8 bfr[8];
#pragma unroll
        for (int nt = 0; nt < 8; nt++)
            bfr[nt] = *(const s16x8*)(Bw + ((size_t)(nt * 16 + m16)) * 128 + ks * 32 + g * 8);
        s16x8 afr[2];
#pragma unroll
        for (int mt = 0; mt < 2; mt++)
            afr[mt] = *(const s16x8*)(Alds + (mt * 16 + m16) * 136 + ks * 32 + g * 8);
#pragma unroll
        for (int mt = 0; mt < 2; mt++)
#pragma unroll
            for (int nt = 0; nt < 8; nt++)
                acc[mt][nt] = __builtin_amdgcn_mfma_f32_16x16x32_bf16(
                    afr[mt], bfr[nt], acc[mt][nt], 0, 0, 0);
    }

    // epilogue: bias, f16 convert, interleave into OT, coalesced global write
    float bias[8];
#pragma unroll
    for (int nt = 0; nt < 8; nt++) bias[nt] = 0.f;
    if (cb == 0) {
#pragma unroll
        for (int nt = 0; nt < 8; nt++) bias[nt] = bf[nt * 16 + m16];
    } else if (cb == 2) {
#pragma unroll
        for (int nt = 0; nt < 8; nt++) bias[nt] = bs[nt * 16 + m16];
    }
    ushort* OT = (cb & 1) ? OTj : OTi;
    const int sel = cb >> 1;
#pragma unroll
    for (int mt = 0; mt < 2; mt++)
#pragma unroll
        for (int nt = 0; nt < 8; nt++)
#pragma unroll
            for (int r = 0; r < 4; r++)
                OT[(mt * 16 + g * 4 + r) * 264 + (nt * 16 + m16) * 2 + sel] =
                    f2h(acc[mt][nt][r] + bias[nt]);
    __syncthreads();
#pragma unroll
    for (int p = 0; p < 4; p++) {
        int idx = t + p * 256;
        int row = idx >> 5, col8 = idx & 31;
        int node = n0 + row;
        if (node < NN) {
            *(uint4*)(Pi + (size_t)node * 256 + col8 * 8) = *(const uint4*)(OTi + row * 264 + col8 * 8);
            *(uint4*)(Pj + (size_t)node * 256 + col8 * 8) = *(const uint4*)(OTj + row * 264 + col8 * 8);
        }
    }
}

// ------- edge kernel (R12 best-known: T14 async-stage, f16 pipeline, run-hoisted Pi):
//   prologue: issue se/sdst window + all Pj gathers + initial Pi row
//   phase1:   E = ea @ Wte via f16 MFMA -> Elds
//   phase2:   consume prefetched registers; Elds reads; gate; run-batched atomics -------
__global__ __launch_bounds__(256) void k_edge(const ushort* __restrict__ Pi,
        const ushort* __restrict__ Pj, const uint2* __restrict__ se,
        const int* __restrict__ sdst, const float* __restrict__ ea,
        const ushort* __restrict__ Wte, float* __restrict__ A) {
    __shared__ ushort Elds[32 * 264];   // [32 edges][256 n + 8 pad] f16
    const int t = threadIdx.x, w = t >> 6, l = t & 63;
    const int bid = xcd_swz(blockIdx.x, gridDim.x);
    const int e0 = bid * 32;
    const int m16 = l & 15, g = l >> 4;

    // ---- prologue: phase-2 gather issue (overlaps phase 1 + barrier) ----
    const uint* PiU = (const uint*)Pi;
    const uint* PjU = (const uint*)Pj;
    const int base = e0 + w * 8;
    uint mysrc = se[base + (l & 7)].x;       // one load covers wave's 8 edges
    int  mydst = sdst[base + (l & 7)];
    int dsts[8];
    uint pj0a[8], pj1a[8];
#pragma unroll
    for (int i = 0; i < 8; i++) {
        const int src = __builtin_amdgcn_readlane((int)mysrc, i);
        dsts[i] = __builtin_amdgcn_readlane(mydst, i);
        const uint* pjb = PjU + (size_t)src * 128;   // scalar base -> saddr loads
        pj0a[i] = pjb[l];
        pj1a[i] = pjb[64 + l];
    }
    int dcur = dsts[0];
    const uint* pib0 = PiU + (size_t)dcur * 128;
    uint pi0 = pib0[l], pi1 = pib0[64 + l];

    // ---- phase 1: E = ea_f16 @ Wte (M=32 sorted edges via eid, N=256, K=64) ----
    f16x8 bt[4][2];
#pragma unroll
    for (int nt = 0; nt < 4; nt++)
#pragma unroll
        for (int ks = 0; ks < 2; ks++)
            bt[nt][ks] = *(const f16x8*)(Wte + ((size_t)(w * 64 + nt * 16 + m16)) * 64 + ks * 32 + g * 8);

    f16x8 at[2][2];
#pragma unroll
    for (int mt = 0; mt < 2; mt++) {
        uint2 s2 = se[e0 + mt * 16 + m16];
        const float* row = ea + (size_t)s2.y * DE;
        f32x4u q0 = *(const f32x4u*)(row + g * 8);
        f32x4u q1 = *(const f32x4u*)(row + g * 8 + 4);
        float v0[8] = {q0.x, q0.y, q0.z, q0.w, q1.x, q1.y, q1.z, q1.w};
        at[mt][0] = pack8h(v0);
        float v1[8] = {0.f, 0.f, 0.f, 0.f, 0.f, 0.f, 0.f, 0.f};
        if (g == 0) {
            f32x4u q2 = *(const f32x4u*)(row + 32);
            f32x4u q3 = *(const f32x4u*)(row + 36);
            v1[0] = q2.x; v1[1] = q2.y; v1[2] = q2.z; v1[3] = q2.w;
            v1[4] = q3.x; v1[5] = q3.y; v1[6] = q3.z; v1[7] = q3.w;
        } else if (g == 1) {
            v1[0] = row[40];
        }
        at[mt][1] = pack8h(v1);
    }

    f32x4 acc[2][4];
#pragma unroll
    for (int mt = 0; mt < 2; mt++)
#pragma unroll
        for (int nt = 0; nt < 4; nt++)
            acc[mt][nt] = (f32x4){0.f, 0.f, 0.f, 0.f};
#pragma unroll
    for (int ks = 0; ks < 2; ks++)
#pragma unroll
        for (int mt = 0; mt < 2; mt++)
#pragma unroll
            for (int nt = 0; nt < 4; nt++)
                acc[mt][nt] = __builtin_amdgcn_mfma_f32_16x16x32_f16(
                    at[mt][ks], bt[nt][ks], acc[mt][nt], 0, 0, 0);

    // write E to LDS: D layout col = lane&15 (n), row = (lane>>4)*4 + reg (m)
#pragma unroll
    for (int mt = 0; mt < 2; mt++)
#pragma unroll
        for (int nt = 0; nt < 4; nt++) {
            uint u01 = pkh1(acc[mt][nt][0], acc[mt][nt][1]);
            uint u23 = pkh1(acc[mt][nt][2], acc[mt][nt][3]);
            const int col = w * 64 + nt * 16 + m16;
            const int r0 = mt * 16 + g * 4;
            Elds[(r0 + 0) * 264 + col] = (ushort)u01;
            Elds[(r0 + 1) * 264 + col] = (ushort)(u01 >> 16);
            Elds[(r0 + 2) * 264 + col] = (ushort)u23;
            Elds[(r0 + 3) * 264 + col] = (ushort)(u23 >> 16);
        }
    __syncthreads();

    // ---- phase 2: consume prefetched data; wave w -> edges w*8..w*8+7 ----
    const uint* ElU = (const uint*)Elds;
    float msg0[8], msg1[8];
#pragma unroll
    for (int i = 0; i < 8; i++) {
        if (dsts[i] != dcur) {                        // wave-uniform scalar branch
            dcur = dsts[i];
            const uint* pb = PiU + (size_t)dcur * 128;
            pi0 = pb[l];
            pi1 = pb[64 + l];
        }
        uint ev0 = ElU[(w * 8 + i) * 132 + l];
        uint ev1 = ElU[(w * 8 + i) * 132 + 64 + l];
        f16x2 t0 = u2h(pi0) + u2h(pj0a[i]) + u2h(ev0);   // v_pk_add_f16
        f16x2 t1 = u2h(pi1) + u2h(pj1a[i]) + u2h(ev1);
        msg0[i] = gate((float)t0.x, (float)t0.y);
        msg1[i] = gate((float)t1.x, (float)t1.y);
    }
    float c0 = msg0[0], c1 = msg1[0];
    int dprev = dsts[0];
#pragma unroll
    for (int i = 1; i < 8; i++) {
        if (dsts[i] == dprev) { c0 += msg0[i]; c1 += msg1[i]; }
        else {
            atomicAdd(A + (size_t)dprev * DH + l, c0);
            atomicAdd(A + (size_t)dprev * DH + 64 + l, c1);
            c0 = msg0[i]; c1 = msg1[i]; dprev = dsts[i];
        }
    }
    atomicAdd(A + (size_t)dprev * DH + l, c0);
    atomicAdd(A + (size_t)dprev * DH + 64 + l, c1);
}

// ---------------- elementwise leaky on A; refresh Abf ----------------
__global__ __launch_bounds__(256) void k_act(float* __restrict__ A,
        ushort* __restrict__ Abf) {
    int i = blockIdx.x * 256 + threadIdx.x;
    float4* A4 = (float4*)A;
    float4 v = A4[i];
    v.x = leaky(v.x); v.y = leaky(v.y); v.z = leaky(v.z); v.w = leaky(v.w);
    A4[i] = v;
    ((uint2*)Abf)[i] = make_uint2(cvtpk1(v.x, v.y), cvtpk1(v.z, v.w));
}

// ------- final activation + embs write + pooling with run-batched atomics -------
// batch is SORTED: wave w handles 8 consecutive nodes (channels l, l+64),
// accumulates runs of equal graph-id in registers, flushes at boundaries.
__global__ __launch_bounds__(256) void k_finalize(const float* __restrict__ A,
        const int* __restrict__ batch, float* __restrict__ embs,
        float* __restrict__ pooled) {
    const int t = threadIdx.x, w = t >> 6, l = t & 63;
    const int n0 = blockIdx.x * 32 + w * 8;
    int idx = n0 + (l & 7);
    int myb = batch[min(idx, NN - 1)];
    float c0 = 0.f, c1 = 0.f;
    int bprev = __builtin_amdgcn_readlane(myb, 0);
#pragma unroll
    for (int i = 0; i < 8; i++) {
        const int n = n0 + i;
        const int b = __builtin_amdgcn_readlane(myb, i);
        float v0 = 0.f, v1 = 0.f;
        if (n < NN) {
            v0 = leaky(A[(size_t)n * DH + l]);
            v1 = leaky(A[(size_t)n * DH + 64 + l]);
            embs[(size_t)n * DH + l] = v0;
            embs[(size_t)n * DH + 64 + l] = v1;
        }
        if (b != bprev) {
            atomicAdd(pooled + (size_t)bprev * DH + l, c0);
            atomicAdd(pooled + (size_t)bprev * DH + 64 + l, c1);
            c0 = v0; c1 = v1; bprev = b;
        } else {
            c0 += v0; c1 += v1;
        }
    }
    atomicAdd(pooled + (size_t)bprev * DH + l, c0);
    atomicAdd(pooled + (size_t)bprev * DH + 64 + l, c1);
}

// ---------------- head: normalize, W1+leaky, W2 ----------------
__global__ __launch_bounds__(128) void k_head(const float* __restrict__ pooled,
        const float* __restrict__ W1, const float* __restrict__ b1,
        const float* __restrict__ W2, const float* __restrict__ b2,
        float* __restrict__ out) {
    __shared__ __align__(16) float gl[128];
    __shared__ float red[2];
    const int g = blockIdx.x, o = threadIdx.x;
    const int l = o & 63, wid = o >> 6;
    float p = pooled[(size_t)g * DH + o];
    float v = p * p;
#pragma unroll
    for (int off = 32; off >= 1; off >>= 1) v += __shfl_xor(v, off);
    if (l == 0) red[wid] = v;
    __syncthreads();
    float nrm = fmaxf(sqrtf(red[0] + red[1]), 1e-12f);
    float gv = p / nrm;
    gl[o] = gv;
    __syncthreads();
    float gm = b1[o];
    const float4* Wr = (const float4*)(W1 + (size_t)o * DH);
    const float4* gl4 = (const float4*)gl;
    for (int kk = 0; kk < 32; kk++) {
        float4 w = Wr[kk]; float4 a = gl4[kk];
        gm = fmaf(w.x, a.x, gm); gm = fmaf(w.y, a.y, gm);
        gm = fmaf(w.z, a.z, gm); gm = fmaf(w.w, a.w, gm);
    }
    gm = leaky(gm);
    float c = gm * W2[o];
#pragma unroll
    for (int off = 32; off >= 1; off >>= 1) c += __shfl_xor(c, off);
    __syncthreads();
    if (l == 0) red[wid] = c;
    __syncthreads();
    if (o == 0) out[g] = red[0] + red[1] + b2[0];
}

extern "C" void kernel_launch(void* const* d_in, const int* in_sizes, int n_in,
                              void* d_out, int out_size, void* d_ws, size_t ws_size,
                              hipStream_t stream) {
    const float* x    = (const float*)d_in[0];
    const int*   ei   = (const int*)d_in[1];
    const float* ea   = (const float*)d_in[2];
    const int*   batch= (const int*)d_in[3];
    const float* Wn   = (const float*)d_in[4];
    const float* bn   = (const float*)d_in[5];
    const float* Wf1  = (const float*)d_in[6];
    const float* bf1  = (const float*)d_in[7];
    const float* Ws1  = (const float*)d_in[8];
    const float* bs1  = (const float*)d_in[9];
    const float* Wf2  = (const float*)d_in[10];
    const float* bf2  = (const float*)d_in[11];
    const float* Ws2  = (const float*)d_in[12];
    const float* bs2  = (const float*)d_in[13];
    const float* W1   = (const float*)d_in[14];
    const float* b1   = (const float*)d_in[15];
    const float* W2   = (const float*)d_in[16];
    const float* b2   = (const float*)d_in[17];

    float* ws      = (float*)d_ws;
    float*  A      = ws + OFF_A;
    ushort* Abf    = (ushort*)(ws + OFF_ABF);
    ushort* Pi     = (ushort*)(ws + OFF_PI);
    ushort* Pj     = (ushort*)(ws + OFF_PJ);
    ushort* Wcatb  = (ushort*)(ws + OFF_WCATB);
    ushort* Wte    = (ushort*)(ws + OFF_WTE);
    float*  pooled = ws + OFF_POOL;
    int*    cnt    = (int*)(ws + OFF_CNT);
    int*    cur    = (int*)(ws + OFF_CUR);
    uint2*  se     = (uint2*)(ws + OFF_SE);
    int*    sdst   = (int*)(ws + OFF_SDST);
    int*    part   = (int*)(ws + OFF_PART);
    int*    boff   = (int*)(ws + OFF_BOFF);
    float* out     = (float*)d_out;
    float* embs    = out + NG;

    const int NBLK = (NN + 255) / 256;   // 196 scan blocks

    hipMemsetAsync(pooled, 0, (size_t)NG * DH * sizeof(float), stream);
    hipMemsetAsync(cnt, 0, (size_t)NN * sizeof(int), stream);
    k_pack_wcatb<<<1024, 128, 0, stream>>>(Wf1, Ws1, Wf2, Ws2, Wcatb);
    k_pack_wte<<<dim3(256, 2), 64, 0, stream>>>(Wf1, Ws1, Wf2, Ws2, Wte);
    k_node_embed<<<NN / 16, 128, 0, stream>>>(x, Wn, bn, A, Abf);

    // sort edges by dst (shared by both layers); 3-pass parallel scan
    k_hist<<<NE / 256, 256, 0, stream>>>(ei, cnt);
    k_scan1<<<NBLK, 256, 0, stream>>>(cnt, part);
    k_scan2<<<1, 256, 0, stream>>>(part, boff, NBLK);
    k_scan3<<<NBLK, 256, 0, stream>>>(cnt, boff, cur);
    k_scatter<<<NE / 256, 256, 0, stream>>>(ei, cur, se, sdst);

    // layer 1
    k_gemm_P2<<<(NN + 31) / 32, 256, 0, stream>>>(Abf, Wcatb, bf1, bs1, Pi, Pj);
    k_edge<<<NE / 32, 256, 0, stream>>>(Pi, Pj, se, sdst, ea, Wte, A);
    k_act<<<(NN * DH / 4) / 256, 256, 0, stream>>>(A, Abf);

    // layer 2
    k_gemm_P2<<<(NN + 31) / 32, 256, 0, stream>>>(Abf, Wcatb + (size_t)512 * 128, bf2, bs2, Pi, Pj);
    k_edge<<<NE / 32, 256, 0, stream>>>(Pi, Pj, se, sdst, ea, Wte + (size_t)256 * 64, A);

    k_finalize<<<(NN + 31) / 32, 256, 0, stream>>>(A, batch, embs, pooled);
    k_head<<<NG, 128, 0, stream>>>(pooled, W1, b1, W2, b2, out);
}